// Round 8
// baseline (71.141 us; speedup 1.0000x reference)
//
#include <hip/hip_runtime.h>

// casConv2d: B=1, C=128, H=W=32, OC=128, K=3, pad=1, stride=1.
// L = 1024, CKK = 1152 = 36 exact 32-tap chunks (reference front-pad chunk == 0).
//
// Round-16. R7 post-mortem: 512-thr blocks (2 waves/SIMD) -> total 69.5,
// fused ~14.5us. Remaining gap vs ~4.5us issue model: each block streams the
// ENTIRE 576KB wt4 from L2 (never L1-resident); per-CU L2 BW ~56B/cyc ->
// ~4.4us hard W-stream floor (aggregate check: 147MB/34.5TB/s = 4.3us).
// Kernel is L2-W-stream bound with only 2 waves/SIMD of overlap.
//
// R8: occupancy 3 waves/SIMD, nothing else. 768-thread blocks, same 256-block
// grid: 6 groups x 128 threads, 6 chunks each (exact 36=6x6; 1024-thr would
// hit the VGPR<=128 cliff + ragged 4.5-chunk split). VGPR cap at 3 w/SIMD is
// 170 (current ~130 fits); LDS 90KB = 1 block/CU. Fully-unrolled 6-chunk
// ping-pong keeps 2-deep W prefetch. vbuf contents, totals order, and the
// verified epilogue (threads 0-255) untouched -> bit-identical numerics,
// absmax 0.03515625 expected.
#define L_    1024
#define CKK_  1152
#define QMAX_ 255.0f
#define NCH   36

// ---- W transpose: w[oc][1152] -> wt4[tq][oc] (tq = tap quad, 288x128 f4) ----
__global__ __launch_bounds__(256) void wtrans(
    const float* __restrict__ w, float* __restrict__ wt)
{
    const int e  = blockIdx.x * 256 + threadIdx.x;   // 36864 float4 slots
    const int oc = e / 288, tq = e - 288 * oc;
    const float4 v = ((const float4*)(w + oc * CKK_))[tq];   // coalesced read
    ((float4*)wt)[tq * 128 + oc] = v;                        // scattered write (L2)
}

template <bool WT>
__global__ __launch_bounds__(768) void fused_cas(
    const float* __restrict__ x,      // [128][32][32]
    const float* __restrict__ w,      // [128][1152]        (WT=false path)
    const float4* __restrict__ wt4,   // [288][128] float4  (WT=true path)
    const float* __restrict__ bias,   // [128]
    float* __restrict__ out)          // [128][1024]
{
    __shared__ __align__(16) float  xs[NCH * 32 * 4];   // [j][tap][px], 18 KB
    __shared__ __align__(16) float4 vbuf[NCH][128];     // [j][oc] px0..3, 72 KB
    __shared__ float red[12][4];                        // per-wave {mn0,mx0,mn1,mx1}
    __shared__ float spar[2][2][3];                     // [ppe][s]{sc,zp,iv}
    __shared__ float qb[4][128];                        // [px-local][oc]

    const int t   = threadIdx.x;                        // 0..767
    const int b   = blockIdx.x;
    const int oc  = t & 127;
    const int g   = t >> 7;            // chunk-ownership group (6 x 2 waves)
    const int ppe = g & 1;             // epilogue px-pair (threads 0..255)
    const int oh  = b >> 3;            // all 4 px share one output row
    const int ow0 = (b & 7) * 4;
    const int l0  = b * 4;

    // ---- prologue: stage ALL x for this block (4608 elems = 6/thread) ----
    for (int i = 0; i < 6; ++i) {
        const int e   = i * 768 + t;
        const int j   = e >> 7;            // chunk
        const int tap = (e >> 2) & 31;
        const int px  = e & 3;
        const int d   = j * 32 + tap;
        const int c   = d / 9, r = d - 9 * c;
        const int kh  = r / 3, kw = r - 3 * kh;
        const int iy  = oh + kh - 1, ix = ow0 + px + kw - 1;
        const bool ok = ((unsigned)iy < 32u) & ((unsigned)ix < 32u);
        const float vv = x[ok ? (c * 1024 + iy * 32 + ix) : 0];
        xs[e] = ok ? vv : 0.f;
    }
    __syncthreads();

    // ---- main loop: group g owns chunks [6g, 6g+6) for ALL 4 px ----
    const float4* wrow = (const float4*)(w + oc * CKK_);

    auto load8 = [&](float4* dst, int j) {
#pragma unroll
        for (int k4 = 0; k4 < 8; ++k4)
            dst[k4] = WT ? wt4[(j * 8 + k4) * 128 + oc] : wrow[j * 8 + k4];
    };

    auto chunk = [&](int j, const float4* wreg) {
        float a0 = 0.f, a1 = 0.f, a2 = 0.f, a3 = 0.f;
        const float4* xj = (const float4*)(xs + j * 128);  // [tap] -> 4 px
#pragma unroll
        for (int k4 = 0; k4 < 8; ++k4) {
            const float4 wv = wreg[k4];
            const float4 x0 = xj[4 * k4 + 0];
            const float4 x1 = xj[4 * k4 + 1];
            const float4 x2 = xj[4 * k4 + 2];
            const float4 x3 = xj[4 * k4 + 3];
            a0 = fmaf(wv.x, x0.x, a0); a1 = fmaf(wv.x, x0.y, a1);
            a2 = fmaf(wv.x, x0.z, a2); a3 = fmaf(wv.x, x0.w, a3);
            a0 = fmaf(wv.y, x1.x, a0); a1 = fmaf(wv.y, x1.y, a1);
            a2 = fmaf(wv.y, x1.z, a2); a3 = fmaf(wv.y, x1.w, a3);
            a0 = fmaf(wv.z, x2.x, a0); a1 = fmaf(wv.z, x2.y, a1);
            a2 = fmaf(wv.z, x2.z, a2); a3 = fmaf(wv.z, x2.w, a3);
            a0 = fmaf(wv.w, x3.x, a0); a1 = fmaf(wv.w, x3.y, a1);
            a2 = fmaf(wv.w, x3.z, a2); a3 = fmaf(wv.w, x3.w, a3);
        }
        vbuf[j][oc] = make_float4(a0, a1, a2, a3);   // group-private slot
    };

    {
        const int jb = g * 6;
        float4 wc[8], wn[8];
        load8(wc, jb + 0);
        load8(wn, jb + 1);
        chunk(jb + 0, wc); load8(wc, jb + 2);
        chunk(jb + 1, wn); load8(wn, jb + 3);
        chunk(jb + 2, wc); load8(wc, jb + 4);
        chunk(jb + 3, wn); load8(wn, jb + 5);
        chunk(jb + 4, wc);
        chunk(jb + 5, wn);
    }
    __syncthreads();   // vbuf complete across groups

    // ---- totals: exact R5/R6/R7 summation order (j ascending, then +bias).
    // Threads 256-767 compute benign duplicates (red slots 4..11 unread).
    float s0 = 0.f, s1 = 0.f;
    for (int j = 0; j < NCH; ++j) {
        const float4 vv = vbuf[j][oc];
        s0 += (ppe == 0) ? vv.x : vv.z;
        s1 += (ppe == 0) ? vv.y : vv.w;
    }
    const float bval = bias[oc];
    const float t0 = s0 + bval, t1 = s1 + bval;

    // ---- minmax + scale/zp (verbatim R7, verified) ----
    float mn0 = t0, mx0 = t0, mn1 = t1, mx1 = t1;
#pragma unroll
    for (int off = 32; off > 0; off >>= 1) {
        mn0 = fminf(mn0, __shfl_xor(mn0, off));
        mx0 = fmaxf(mx0, __shfl_xor(mx0, off));
        mn1 = fminf(mn1, __shfl_xor(mn1, off));
        mx1 = fmaxf(mx1, __shfl_xor(mx1, off));
    }
    const int wv = t >> 6;                  // 0..11
    if ((t & 63) == 0) {
        red[wv][0] = mn0; red[wv][1] = mx0;
        red[wv][2] = mn1; red[wv][3] = mx1;
    }
    __syncthreads();
    if ((t & 63) == 0 && (wv & 1) == 0 && wv < 4) {  // waves 0,2 finalize ppe
        const int pw = wv ^ 1;
        const float amn0 = fminf(mn0, red[pw][0]);
        const float amx0 = fmaxf(mx0, red[pw][1]);
        const float amn1 = fminf(mn1, red[pw][2]);
        const float amx1 = fmaxf(mx1, red[pw][3]);
        {
            const float sv = (amx0 - amn0) / QMAX_;
            float z = -amn0 / sv;
            z = fmaxf(z, 0.f);      // fmaxf(NaN,0)=0 matches where(isnan,0)
            z = fminf(z, QMAX_);
            z = truncf(z);
            spar[ppe][0][0] = sv; spar[ppe][0][1] = z; spar[ppe][0][2] = 1.0f / sv;
        }
        {
            const float sv = (amx1 - amn1) / QMAX_;
            float z = -amn1 / sv;
            z = fmaxf(z, 0.f);
            z = fminf(z, QMAX_);
            z = truncf(z);
            spar[ppe][1][0] = sv; spar[ppe][1][1] = z; spar[ppe][1][2] = 1.0f / sv;
        }
    }
    __syncthreads();

    // ---- fake-quant accumulate (j ascending, same ops as R7) ----
    const float sc0 = spar[ppe][0][0], zp0 = spar[ppe][0][1], iv0 = spar[ppe][0][2];
    const float sc1 = spar[ppe][1][0], zp1 = spar[ppe][1][1], iv1 = spar[ppe][1][2];
    float q0 = 0.f, q1 = 0.f;
    for (int j = 0; j < NCH; ++j) {
        const float4 vv = vbuf[j][oc];
        const float v0 = (ppe == 0) ? vv.x : vv.z;
        const float v1 = (ppe == 0) ? vv.y : vv.w;
        float qn0 = rintf(v0 * iv0) + zp0;   // rintf == round-half-even
        qn0 = fminf(fmaxf(qn0, 0.f), QMAX_);
        q0 += (qn0 - zp0) * sc0;
        float qn1 = rintf(v1 * iv1) + zp1;
        qn1 = fminf(fmaxf(qn1, 0.f), QMAX_);
        q1 += (qn1 - zp1) * sc1;
    }
    if (t < 256) {
        qb[2 * ppe + 0][oc] = q0;
        qb[2 * ppe + 1][oc] = q1;
    }
    __syncthreads();

    if (t < 128)
        *(float4*)(out + (size_t)t * L_ + l0) =
            make_float4(qb[0][t], qb[1][t], qb[2][t], qb[3][t]);
}

extern "C" void kernel_launch(void* const* d_in, const int* in_sizes, int n_in,
                              void* d_out, int out_size, void* d_ws, size_t ws_size,
                              hipStream_t stream) {
    const float* x    = (const float*)d_in[0];  // 128*32*32
    const float* w    = (const float*)d_in[1];  // 128*1152
    const float* bias = (const float*)d_in[2];  // 128
    float* out = (float*)d_out;                 // 128*1024
    float* ws  = (float*)d_ws;

    const size_t wt_need = (size_t)288 * 128 * 16;   // 576 KB
    if (ws_size >= wt_need) {
        wtrans<<<144, 256, 0, stream>>>((const float*)d_in[1], ws);
        fused_cas<true><<<256, 768, 0, stream>>>(
            x, w, (const float4*)ws, bias, out);
    } else {
        fused_cas<false><<<256, 768, 0, stream>>>(
            x, w, nullptr, bias, out);
    }
}